// Round 1
// baseline (439.467 us; speedup 1.0000x reference)
//
#include <hip/hip_runtime.h>
#include <hip/hip_bf16.h>
#include <cstddef>

#define B_   2
#define LQ_  2048
#define LK_  2048
#define H_   8
#define D_   32
#define QB   16      // queries per block
#define KB   32      // keys per chunk
#define NW   4       // waves per block
#define QPW  4       // queries per wave
#define NCH  (LK_/KB)

// ws layout (floats)
#define OFF_QIT  0
#define OFF_QC   131072      // B*LQ*32
#define OFF_KIT  262144
#define OFF_KC   393216
#define OFF_V    524288      // B*LK*256 floats follow

// ---------------------------------------------------------------------------
// Fused small projections: Qit, Qc, Kit, Kc  (all [4096 rows] x 32 cols)
// ---------------------------------------------------------------------------
__global__ __launch_bounds__(256)
void proj_qk_kernel(const float* __restrict__ Aq_it, const float* __restrict__ Aq_c,
                    const float* __restrict__ Ak_it, const float* __restrict__ Ak_c,
                    const float* __restrict__ Wq_it, const float* __restrict__ Wq_c,
                    const float* __restrict__ Wk_it, const float* __restrict__ Wk_c,
                    float* __restrict__ ws)
{
    int idx = blockIdx.x * 256 + threadIdx.x;      // 0 .. 4*131072-1
    int seg = idx >> 17;                           // 0..3
    int off = idx & 131071;
    int r = off >> 5;                              // row 0..4095
    int c = off & 31;
    const float* A; const float* W; int K; float* O;
    if (seg == 0)      { A = Aq_it; W = Wq_it; K = 256; O = ws + OFF_QIT; }
    else if (seg == 1) { A = Aq_c;  W = Wq_c;  K = 128; O = ws + OFF_QC;  }
    else if (seg == 2) { A = Ak_it; W = Wk_it; K = 256; O = ws + OFF_KIT; }
    else               { A = Ak_c;  W = Wk_c;  K = 128; O = ws + OFF_KC;  }
    const float* a = A + (size_t)r * K;
    float s = 0.f;
    #pragma unroll 8
    for (int k = 0; k < K; ++k)
        s = fmaf(a[k], W[k * 32 + c], s);
    O[off] = s;
}

// ---------------------------------------------------------------------------
// V projection: keys_it [4096,256] @ Wv [256,256] -> V [4096,256]
// Tile: 32 rows x 256 cols per block. A^T staged in LDS (wave-uniform b128
// broadcast reads); W streamed from global (L2-resident, 256 KB).
// ---------------------------------------------------------------------------
__global__ __launch_bounds__(256)
void proj_v_kernel(const float* __restrict__ A, const float* __restrict__ Wv,
                   float* __restrict__ Vout)
{
    __shared__ float AsT[256][36];                 // [k][row], stride 36 for f4 align
    const int tid = threadIdx.x;
    const int r0  = blockIdx.x * 32;

    const float4* src = (const float4*)(A + (size_t)r0 * 256);
    #pragma unroll
    for (int i = 0; i < 8; ++i) {
        int idx4 = tid + 256 * i;
        int row  = idx4 >> 6;                      // 0..31
        int c4   = idx4 & 63;
        float4 v = src[idx4];
        AsT[c4 * 4 + 0][row] = v.x;
        AsT[c4 * 4 + 1][row] = v.y;
        AsT[c4 * 4 + 2][row] = v.z;
        AsT[c4 * 4 + 3][row] = v.w;
    }
    __syncthreads();

    const int rg = tid >> 6;                       // wave id: rows rg*8..rg*8+7
    const int c  = tid & 63;                       // cols c, c+64, c+128, c+192
    float acc[8][4];
    #pragma unroll
    for (int j = 0; j < 8; ++j)
        #pragma unroll
        for (int cc = 0; cc < 4; ++cc) acc[j][cc] = 0.f;

    for (int k = 0; k < 256; ++k) {
        float4 a0 = *((const float4*)&AsT[k][rg * 8]);
        float4 a1 = *((const float4*)&AsT[k][rg * 8 + 4]);
        float wv[4];
        #pragma unroll
        for (int cc = 0; cc < 4; ++cc) wv[cc] = Wv[(size_t)k * 256 + c + 64 * cc];
        float aj[8] = {a0.x, a0.y, a0.z, a0.w, a1.x, a1.y, a1.z, a1.w};
        #pragma unroll
        for (int j = 0; j < 8; ++j)
            #pragma unroll
            for (int cc = 0; cc < 4; ++cc)
                acc[j][cc] = fmaf(aj[j], wv[cc], acc[j][cc]);
    }
    #pragma unroll
    for (int j = 0; j < 8; ++j)
        #pragma unroll
        for (int cc = 0; cc < 4; ++cc)
            Vout[(size_t)(r0 + rg * 8 + j) * 256 + c + 64 * cc] = acc[j][cc];
}

// ---------------------------------------------------------------------------
// Fused dual-stream attention, flash-style online softmax.
// Block: 16 queries, 4 waves (each wave: 4 queries). Chunks of 32 keys.
// Score phase: half-wave per query, lane-per-key. PV phase: lane-per-(h,4d).
// ---------------------------------------------------------------------------
__global__ __launch_bounds__(256)
void attn_kernel(const float* __restrict__ ws,
                 const float* __restrict__ q_resid,
                 const float* __restrict__ sigma,
                 const float* __restrict__ noise,
                 const float* __restrict__ Whdp,
                 const float* __restrict__ bhdp,
                 const int* __restrict__ key_mask,
                 const int* __restrict__ query_mask,
                 float* __restrict__ out)
{
    const float* Qit = ws + OFF_QIT;
    const float* Qc  = ws + OFF_QC;
    const float* Kit = ws + OFF_KIT;
    const float* Kc  = ws + OFF_KC;
    const float* V   = ws + OFF_V;

    const int b    = blockIdx.y;
    const int q0   = blockIdx.x * QB;
    const int tid  = threadIdx.x;
    const int w    = tid >> 6;
    const int lane = tid & 63;
    const int half = (lane >> 5) & 1;
    const int lj   = lane & 31;
    const int hl   = lane >> 3;                    // head in PV layout (0..7)

    __shared__ float Qs[QB][64];                   // [ql][0:32 Qit | 32:64 Qc]
    __shared__ float Ks[KB][65];                   // stride 65: conflict-free dot reads
    __shared__ float Vs[KB][256];
    __shared__ float Ps[NW][KB][H_][4];            // [w][k][h XOR (k&7)][i], f4-readable
    __shared__ float Ss[NW][QPW][H_];              // per-chunk rescale
    __shared__ float Ls[NW][QPW][H_];              // final denominators

    // stage Q tile once
    {
        int row = tid >> 4;
        int c4  = tid & 15;
        const float4* qit4 = (const float4*)(Qit + ((size_t)b * LQ_ + q0) * 32);
        const float4* qc4  = (const float4*)(Qc  + ((size_t)b * LQ_ + q0) * 32);
        float4 v = (c4 < 8) ? qit4[row * 8 + c4] : qc4[row * 8 + (c4 - 8)];
        *((float4*)&Qs[row][c4 * 4]) = v;
    }

    float sg0 = sigma[b * 2 + 0]; const float a0 = sg0 * sg0;
    float sg1 = sigma[b * 2 + 1]; const float a1 = sg1 * sg1;
    const float rsd = 0.17677669529663687f;        // 1/sqrt(32)
    float w0s[H_], w1s[H_], bhs[H_];
    #pragma unroll
    for (int h = 0; h < H_; ++h) {
        w0s[h] = Whdp[h]      * rsd;
        w1s[h] = Whdp[H_ + h] * rsd;
        bhs[h] = bhdp[h]      * rsd;
    }

    float m_reg[2][H_], l_reg[2][H_];
    #pragma unroll
    for (int p = 0; p < 2; ++p)
        #pragma unroll
        for (int h = 0; h < H_; ++h) { m_reg[p][h] = -1e30f; l_reg[p][h] = 0.f; }

    float acc[QPW][4];
    #pragma unroll
    for (int i = 0; i < QPW; ++i) { acc[i][0]=acc[i][1]=acc[i][2]=acc[i][3]=0.f; }

    for (int ch = 0; ch < NCH; ++ch) {
        const int k0 = ch * KB;

        // ---- stage Vs (32 rows x 256 floats) ----
        {
            const float4* vsrc = (const float4*)(V + ((size_t)b * LK_ + k0) * 256);
            float4* vdst = (float4*)&Vs[0][0];
            #pragma unroll
            for (int i2 = 0; i2 < 8; ++i2) vdst[tid + 256 * i2] = vsrc[tid + 256 * i2];
        }
        // ---- stage Ks (Kit | Kc, 32 rows x 64 floats) ----
        {
            const int j  = tid >> 3;
            const int t0 = (tid & 7) * 8;
            const float* srcrow;
            if (t0 < 32) srcrow = Kit + ((size_t)b * LK_ + k0 + j) * 32 + t0;
            else         srcrow = Kc  + ((size_t)b * LK_ + k0 + j) * 32 + (t0 - 32);
            float4 va = *((const float4*)srcrow);
            float4 vb = *((const float4*)(srcrow + 4));
            float* kd = &Ks[j][t0];
            kd[0]=va.x; kd[1]=va.y; kd[2]=va.z; kd[3]=va.w;
            kd[4]=vb.x; kd[5]=vb.y; kd[6]=vb.z; kd[7]=vb.w;
        }
        __syncthreads();

        const bool kmb = key_mask[b * LK_ + k0 + lj] != 0;

        // ---- score phase: 2 passes, half-wave per query ----
        #pragma unroll
        for (int p = 0; p < 2; ++p) {
            const int i  = p * 2 + half;           // local query within wave
            const int ql = w * QPW + i;
            const int q  = q0 + ql;
            const size_t nbase = (((size_t)b * 2) * LQ_ + q) * (size_t)LK_ + k0 + lj;
            const float n0 = noise[nbase];
            const float n1 = noise[nbase + (size_t)LQ_ * LK_];

            float sit = 0.f, sctx = 0.f;
            #pragma unroll
            for (int t = 0; t < 32; ++t) {
                sit  = fmaf(Qs[ql][t],      Ks[lj][t],      sit);
                sctx = fmaf(Qs[ql][32 + t], Ks[lj][32 + t], sctx);
            }
            const float u = fmaf(a0, n0, sit);
            const float v = fmaf(a1, n1, sctx);

            float sc[H_], cm[H_];
            #pragma unroll
            for (int h = 0; h < H_; ++h) {
                sc[h] = kmb ? fmaf(u, w0s[h], fmaf(v, w1s[h], bhs[h])) : -1e30f;
                cm[h] = sc[h];
            }
            // chunk max over the 32 lanes of this half-wave
            #pragma unroll
            for (int d = 1; d < 32; d <<= 1) {
                #pragma unroll
                for (int h = 0; h < H_; ++h)
                    cm[h] = fmaxf(cm[h], __shfl_xor(cm[h], d, 64));
            }
            const int hsw = lj & 7;
            #pragma unroll
            for (int h = 0; h < H_; ++h) {
                const float mold = m_reg[p][h];
                const float mnew = fmaxf(mold, cm[h]);
                const float scl  = __expf(mold - mnew);     // uniform in half-wave
                m_reg[p][h] = mnew;
                const float ph = kmb ? __expf(sc[h] - mnew) : 0.f;
                l_reg[p][h] = fmaf(l_reg[p][h], scl, ph);   // distributed partial sum
                Ps[w][lj][h ^ hsw][i] = ph;                 // swizzled transpose
                Ss[w][i][h] = scl;                          // uniform value, benign
            }
        }
        __syncthreads();

        // ---- PV phase: lane owns (head hl, 4 dims at col lane*4) ----
        #pragma unroll
        for (int i = 0; i < QPW; ++i) {
            const float s = Ss[w][i][hl];
            acc[i][0] *= s; acc[i][1] *= s; acc[i][2] *= s; acc[i][3] *= s;
        }
        for (int j = 0; j < KB; ++j) {
            const float4 v4 = *((const float4*)&Vs[j][lane * 4]);
            const float4 pv = *((const float4*)&Ps[w][j][hl ^ (j & 7)][0]);
            acc[0][0]=fmaf(pv.x,v4.x,acc[0][0]); acc[0][1]=fmaf(pv.x,v4.y,acc[0][1]);
            acc[0][2]=fmaf(pv.x,v4.z,acc[0][2]); acc[0][3]=fmaf(pv.x,v4.w,acc[0][3]);
            acc[1][0]=fmaf(pv.y,v4.x,acc[1][0]); acc[1][1]=fmaf(pv.y,v4.y,acc[1][1]);
            acc[1][2]=fmaf(pv.y,v4.z,acc[1][2]); acc[1][3]=fmaf(pv.y,v4.w,acc[1][3]);
            acc[2][0]=fmaf(pv.z,v4.x,acc[2][0]); acc[2][1]=fmaf(pv.z,v4.y,acc[2][1]);
            acc[2][2]=fmaf(pv.z,v4.z,acc[2][2]); acc[2][3]=fmaf(pv.z,v4.w,acc[2][3]);
            acc[3][0]=fmaf(pv.w,v4.x,acc[3][0]); acc[3][1]=fmaf(pv.w,v4.y,acc[3][1]);
            acc[3][2]=fmaf(pv.w,v4.z,acc[3][2]); acc[3][3]=fmaf(pv.w,v4.w,acc[3][3]);
        }
        __syncthreads();
    }

    // ---- final l reduction (score layout) ----
    #pragma unroll
    for (int p = 0; p < 2; ++p) {
        const int i = p * 2 + half;
        #pragma unroll
        for (int h = 0; h < H_; ++h) {
            float lv = l_reg[p][h];
            #pragma unroll
            for (int d = 1; d < 32; d <<= 1) lv += __shfl_xor(lv, d, 64);
            Ls[w][i][h] = lv;
        }
    }
    __syncthreads();

    // ---- epilogue: normalize, query mask, residual, store (PV layout) ----
    #pragma unroll
    for (int i = 0; i < QPW; ++i) {
        const int q = q0 + w * QPW + i;
        const float qm = (float)query_mask[b * LQ_ + q];
        const float denom = Ls[w][i][hl];
        const float linv = (denom > 0.f) ? (qm / denom) : 0.f;
        const size_t o = ((size_t)b * LQ_ + q) * 256 + lane * 4;
        float4 r = *((const float4*)&q_resid[o]);
        r.x = fmaf(acc[i][0], linv, r.x);
        r.y = fmaf(acc[i][1], linv, r.y);
        r.z = fmaf(acc[i][2], linv, r.z);
        r.w = fmaf(acc[i][3], linv, r.w);
        *((float4*)&out[o]) = r;
    }
}

// ---------------------------------------------------------------------------
extern "C" void kernel_launch(void* const* d_in, const int* in_sizes, int n_in,
                              void* d_out, int out_size, void* d_ws, size_t ws_size,
                              hipStream_t stream)
{
    (void)in_sizes; (void)n_in; (void)out_size; (void)ws_size;
    const float* queries_it  = (const float*)d_in[0];
    const float* queries_ctx = (const float*)d_in[1];
    const float* keys_it     = (const float*)d_in[2];
    const float* keys_ctx    = (const float*)d_in[3];
    const float* sigma       = (const float*)d_in[4];
    const float* noise       = (const float*)d_in[5];
    const float* Wq_it       = (const float*)d_in[6];
    const float* Wk_it       = (const float*)d_in[7];
    const float* Wq_ctx      = (const float*)d_in[8];
    const float* Wk_ctx      = (const float*)d_in[9];
    const float* Wv          = (const float*)d_in[10];
    const float* W_hdp       = (const float*)d_in[11];
    const float* b_hdp       = (const float*)d_in[12];
    const int*   key_mask    = (const int*)d_in[13];
    const int*   query_mask  = (const int*)d_in[14];
    float* out = (float*)d_out;
    float* ws  = (float*)d_ws;    // needs 6,291,456 bytes

    proj_qk_kernel<<<dim3(2048), dim3(256), 0, stream>>>(
        queries_it, queries_ctx, keys_it, keys_ctx,
        Wq_it, Wq_ctx, Wk_it, Wk_ctx, ws);

    proj_v_kernel<<<dim3(128), dim3(256), 0, stream>>>(keys_it, Wv, ws + OFF_V);

    attn_kernel<<<dim3(LQ_ / QB, B_), dim3(256), 0, stream>>>(
        ws, queries_it, sigma, noise, W_hdp, b_hdp, key_mask, query_mask, out);
}